// Round 5
// baseline (285.302 us; speedup 1.0000x reference)
//
#include <hip/hip_runtime.h>

// Correlation: out[b, di*9+dj, h, w] = (1/64) * sum_c x1[b,c,h,w] * x2p[b,c,h+di,w+dj]
// x2p = x2 zero-padded by 4 each side. B=8, C=64, H=W=192.
//
// v6 = v5 (150us kernel) + two latency attacks:
//  - Distance-1 channel software pipeline: prefetch ch c+1's x1 float4 (global/L1) and
//    3 x2 ds_read_b128 before ch c's 36 FMAs. v5's VGPR=48 left only ~12 regs for
//    windows -> per-channel LDS/L1 latency fully exposed; with 23% occupancy (9-wave
//    blocks pack SIMDs {3,2,2,2} -> slot-capped at ~2 blocks/CU) TLP can't cover it.
//    Peak live ~64 regs = the (576,4) cap; allocator sinks loads if over (no spill).
//  - XCD image-affinity swizzle: 1152 blocks = 8 images x 144 tiles; hw block n ->
//    image n&7, tile n>>3. Per-XCD working slab (8ch x1+x2 of one image) = 2.4MB < 4MB
//    L2 -> halo re-reads + x1 9-wave re-reads hit L2 (~200cy) instead of HBM (~900cy).
//    Bijective (1152%8==0) -> correctness-safe under any dispatch mapping.
//  - Unchanged from v5: x2 staged via global_load_lds (zero staging regs, no ds_writes,
//    all-lanes-active with zero-page source redirect for halo pad; slot2 guard tid<128
//    is wave-uniform), double-buffered 2x20KB LDS, ONE barrier per chunk, stage(k+1)
//    issued before compute(k).
//  - Known-inert: SQ_LDS_BANK_CONFLICT ~1.59e7 is inherent b128 multi-word
//    serialization (bit-identical v1 vs v5 across different layouts) — not actionable.
//  - Spill canary: WRITE_SIZE must stay ~93MB (output only).

constexpr int MAXD = 4;
constexpr int OD   = 9;
constexpr int ND   = 81;
constexpr int TB_W = 32;
constexpr int TB_H = 8;
constexpr int CK   = 8;     // channels per LDS chunk
constexpr int X2W  = 40;    // TB_W + 2*MAXD
constexpr int X2H  = 16;    // TB_H + 2*MAXD
constexpr int NT   = 576;   // 9 waves

constexpr int Bc = 8, Cc = 64, Hc = 192, Wc = 192;
constexpr int HW = Hc * Wc;
constexpr int NCHUNK = Cc / CK;            // 8
constexpr int CSTEP  = CK * HW;            // float advance per chunk
constexpr int TILE_F = CK * X2H * X2W;     // 5120 floats per buffer
constexpr int NF4    = TILE_F / 4;         // 1280 float4 slots per chunk
constexpr int NTILE  = (Wc / TB_W) * (Hc / TB_H);   // 144 tiles per image
constexpr int NBLK   = NTILE * Bc;                  // 1152

// 16B of guaranteed zeros (device globals are zero-initialized; never written).
__device__ __align__(16) float g_zero4[4];

__device__ inline void gload_lds16(const float* g, float* l) {
    __builtin_amdgcn_global_load_lds(
        (const __attribute__((address_space(1))) void*)g,
        (__attribute__((address_space(3))) void*)l, 16, 0, 0);
}

__global__ __launch_bounds__(NT, 4) void corr_kernel(
    const float* __restrict__ x1, const float* __restrict__ x2,
    float* __restrict__ out)
{
    __shared__ __align__(16) float s2[2][TILE_F];   // 2 x 20 KB

    const int tid = threadIdx.x;
    const int g   = tid & 63;
    const int di  = tid >> 6;        // 0..8, wave-uniform
    const int gw4 = (g & 7) * 4;     // 0..28
    const int gh  = g >> 3;          // 0..7

    // ---- XCD image-affinity swizzle: hw block n -> image n&7, tile n>>3 ----
    const int n    = blockIdx.x;
    const int b    = n & 7;          // == image index (8 XCDs, 8 images)
    const int tile = n >> 3;         // 0..143
    const int ty   = tile / 6;       // 0..23
    const int tx   = tile - ty * 6;  // 0..5
    const int w0 = tx * TB_W;
    const int h0 = ty * TB_H;

    const float* x1b = x1 + (long)b * Cc * HW;
    const float* x2b = x2 + (long)b * Cc * HW;

    // ---------------- prologue: staging slot geometry (once) ----------------
    // 1280 f4 slots/chunk: i=0,1 -> all 576 threads; i=2 -> threads 0..127 (waves 0-1,
    // fully active => wave-uniform guard, safe for gload_lds).
    int  q0, q1, q2;      // per-thread global float offsets (chunk 0)
    bool st0, st1, st2;   // slot in-bounds (else source = zero page)
    {
        auto slot = [&](int i, int& q, bool& st) {
            int idx = tid + i * NT;
            if (idx >= NF4) idx = 0;            // only under the uniform guard
            int c  = idx / (NF4 / CK);          // /160
            int r  = idx - c * (NF4 / CK);
            int y  = r / (X2W / 4);             // /10
            int x4 = r - y * (X2W / 4);
            int gy = h0 + y - MAXD;
            int gx = w0 + x4 * 4 - MAXD;        // f4-aligned: fully in or fully pad
            st = ((unsigned)gy < (unsigned)Hc) && ((unsigned)gx < (unsigned)Wc);
            q  = c * HW + gy * Wc + gx;         // only dereferenced when st
        };
        slot(0, q0, st0);
        slot(1, q1, st1);
        slot(2, q2, st2);
    }

    float acc[OD][4];
#pragma unroll
    for (int dj = 0; dj < OD; ++dj)
#pragma unroll
        for (int p = 0; p < 4; ++p) acc[dj][p] = 0.f;

    // x1 channel-stream offset (this thread's 4 pixels; L1/L2 broadcast, 9 waves share)
    int poff = (h0 + gh) * Wc + (w0 + gw4);
    // LDS read base within a buffer
    const int roff = (gh + di) * X2W + gw4;

    // stage chunk k into buf: all lanes issue; pad lanes read the zero page.
    auto stage = [&](int k, float* buf) {
        const int cb = k * CSTEP;
        float* d = buf + (unsigned)tid * 4;
        const float* z = g_zero4;
        gload_lds16(st0 ? x2b + cb + q0 : z, d);
        gload_lds16(st1 ? x2b + cb + q1 : z, d + NT * 4);
        if (tid < 2 * 64) {   // wave-uniform: waves 0,1 fully active
            gload_lds16(st2 ? x2b + cb + q2 : z, d + 2 * NT * 4);
        }
    };

    // prologue: chunk 0 into buffer 0
    stage(0, s2[0]);
    __syncthreads();   // vmcnt(0) drain + barrier

#pragma unroll 1
    for (int k = 0; k < NCHUNK; ++k) {
        float* bufA = s2[k & 1];          // compute source (staged last iter)
        float* bufB = s2[(k & 1) ^ 1];    // stage dest (fully consumed last iter)

        // issue next chunk's loads first: HBM/L2 latency hides under this chunk's FMAs
        if (k + 1 < NCHUNK) stage(k + 1, bufB);

        // ---- compute, distance-1 software pipeline over channels ----
        float4 a  = *(const float4*)(x1b + poff);
        poff += HW;
        float4 b0 = *(const float4*)(bufA + roff);
        float4 b1 = *(const float4*)(bufA + roff + 4);
        float4 b2 = *(const float4*)(bufA + roff + 8);

#pragma unroll
        for (int c = 0; c < CK; ++c) {
            float4 na, nb0, nb1, nb2;
            if (c + 1 < CK) {              // prefetch channel c+1 before c's FMAs
                const float* wr = bufA + (c + 1) * (X2H * X2W) + roff;
                na  = *(const float4*)(x1b + poff);
                poff += HW;
                nb0 = *(const float4*)(wr);
                nb1 = *(const float4*)(wr + 4);
                nb2 = *(const float4*)(wr + 8);
            }
            float win[12] = {b0.x, b0.y, b0.z, b0.w,
                             b1.x, b1.y, b1.z, b1.w,
                             b2.x, b2.y, b2.z, b2.w};
            float av[4] = {a.x, a.y, a.z, a.w};
#pragma unroll
            for (int dj = 0; dj < OD; ++dj)
#pragma unroll
                for (int p = 0; p < 4; ++p)
                    acc[dj][p] = fmaf(av[p], win[dj + p], acc[dj][p]);
            if (c + 1 < CK) { a = na; b0 = nb0; b1 = nb1; b2 = nb2; }
        }

        __syncthreads();   // drains gload_lds (vmcnt) -> bufB ready for k+1
    }

    // ---- epilogue: 9 float4 stores per thread (mean over C=64)
    const float scale = 1.0f / 64.0f;
    float* ob = out + (((long)b * ND + di * OD) * Hc + (h0 + gh)) * Wc + (w0 + gw4);
#pragma unroll
    for (int dj = 0; dj < OD; ++dj) {
        float4 v;
        v.x = acc[dj][0] * scale;
        v.y = acc[dj][1] * scale;
        v.z = acc[dj][2] * scale;
        v.w = acc[dj][3] * scale;
        *(float4*)(ob + (long)dj * HW) = v;
    }
}

extern "C" void kernel_launch(void* const* d_in, const int* in_sizes, int n_in,
                              void* d_out, int out_size, void* d_ws, size_t ws_size,
                              hipStream_t stream) {
    const float* x1 = (const float*)d_in[0];
    const float* x2 = (const float*)d_in[1];
    float* out = (float*)d_out;
    corr_kernel<<<dim3(NBLK), NT, 0, stream>>>(x1, x2, out);
}